// Round 2
// baseline (613.557 us; speedup 1.0000x reference)
//
#include <hip/hip_runtime.h>

#define NB 32
#define NP 192
#define DM 48          // max_dur
#define ND 80          // DMEL
#define NH 64          // H
#define NT (NP*DM)     // 9216
#define NBP (NB*NP)    // 6144
#define NG (3*NH)      // 192

__device__ __forceinline__ float sigm(float x){ return 1.0f/(1.0f + __expf(-x)); }
__device__ __forceinline__ float tanh_f(float x){ return 1.0f - 2.0f/(1.0f + __expf(2.0f*x)); }

struct Aff { float a0,c0,a1,c1; };
__device__ __forceinline__ Aff make_aff(const float* cw, const float* cb, const float* bg,
                                        const float* bb, const float* bm, const float* bv){
    float s0 = bg[0]*rsqrtf(bv[0]+1e-5f);
    float s1 = bg[1]*rsqrtf(bv[1]+1e-5f);
    Aff A;
    A.a0 = cw[0]*s0; A.c0 = (cb[0]-bm[0])*s0 + bb[0];
    A.a1 = cw[1]*s1; A.c1 = (cb[1]-bm[1])*s1 + bb[1];
    return A;
}
__device__ __forceinline__ float aff(float x, const Aff A){
    float y = fmaxf(fmaf(A.a0, x, A.c0), 0.0f);
    return fmaxf(fmaf(A.a1, y, A.c1), 0.0f);
}

// ---------------- K1: exclusive cumsum of durations -> starts ----------------
__global__ __launch_bounds__(NP) void k_starts(const int* __restrict__ dur,
                                               int* __restrict__ starts){
    __shared__ int s[NP];
    int b = blockIdx.x, p = threadIdx.x;
    int d = dur[b*NP + p];
    s[p] = d;
    __syncthreads();
    #pragma unroll
    for (int off = 1; off < NP; off <<= 1){
        int v = (p >= off) ? s[p - off] : 0;
        __syncthreads();
        s[p] += v;
        __syncthreads();
    }
    starts[b*NP + p] = s[p] - d;   // exclusive
}

// ---------------- K2: gather + affine + gi = x @ Wih_f^T + bih_f ------------
// one block per sequence (bp); 192 threads, thread j computes column j for all 48 rows
__global__ __launch_bounds__(192) void k_gi(const float* __restrict__ mels,
                                            const int* __restrict__ starts,
                                            const float* __restrict__ Wih,
                                            const float* __restrict__ bih,
                                            const float* __restrict__ cw, const float* __restrict__ cb,
                                            const float* __restrict__ bg, const float* __restrict__ bb,
                                            const float* __restrict__ bm, const float* __restrict__ bv,
                                            float* __restrict__ gi, int bp0){
    __shared__ float xs[DM][ND];          // 15360 B
    int bp = bp0 + blockIdx.x;
    int b  = bp / NP;
    int j  = threadIdx.x;
    Aff A = make_aff(cw,cb,bg,bb,bm,bv);
    int st = starts[bp];
    // stage x tile (gather + fused affine), 960 float4s
    for (int i = j; i < DM*(ND/4); i += 192){
        int t  = i / (ND/4);
        int d4 = i % (ND/4);
        int row = st + t; row = (row < NT-1) ? row : (NT-1);
        float4 v = *(const float4*)(mels + ((size_t)b*NT + row)*ND + d4*4);
        v.x = aff(v.x, A); v.y = aff(v.y, A); v.z = aff(v.z, A); v.w = aff(v.w, A);
        *(float4*)&xs[t][d4*4] = v;
    }
    __syncthreads();
    // load Wih row j into registers (80 floats)
    float w[ND];
    const float* Wr = Wih + (size_t)j*ND;
    #pragma unroll
    for (int d4 = 0; d4 < ND/4; ++d4){
        float4 wv = *(const float4*)(Wr + d4*4);
        w[4*d4+0]=wv.x; w[4*d4+1]=wv.y; w[4*d4+2]=wv.z; w[4*d4+3]=wv.w;
    }
    float bj = bih[j];
    float* go = gi + (size_t)(bp - bp0)*DM*NG;
    for (int m = 0; m < DM; ++m){
        float acc = bj;
        #pragma unroll
        for (int d4 = 0; d4 < ND/4; ++d4){
            float4 xv = *(const float4*)&xs[m][d4*4];   // broadcast read
            acc = fmaf(xv.x, w[4*d4+0], acc);
            acc = fmaf(xv.y, w[4*d4+1], acc);
            acc = fmaf(xv.z, w[4*d4+2], acc);
            acc = fmaf(xv.w, w[4*d4+3], acc);
        }
        go[m*NG + j] = acc;
    }
}

// ---------------- K3: masked forward GRU, one wave per sequence -------------
// lane j owns gates (j, 64+j, 128+j); Whh rows held in registers; h in LDS row
__global__ __launch_bounds__(512, 2) void k_gru(const float* __restrict__ gi,
                                                const float* __restrict__ Whh,
                                                const float* __restrict__ bhh,
                                                const int* __restrict__ dur,
                                                float* __restrict__ out, int bp0){
    __shared__ float hs[8][NH];
    int tid = threadIdx.x;
    int w = tid >> 6, j = tid & 63;
    int bp = bp0 + blockIdx.x*8 + w;
    // load 3 Whh rows into registers
    float w0[NH], w1[NH], w2[NH];
    const float* Wr = Whh + (size_t)j*NH;
    const float* Wz = Whh + (size_t)(NH + j)*NH;
    const float* Wn = Whh + (size_t)(2*NH + j)*NH;
    #pragma unroll
    for (int k4 = 0; k4 < NH/4; ++k4){
        float4 a = *(const float4*)(Wr + 4*k4);
        w0[4*k4+0]=a.x; w0[4*k4+1]=a.y; w0[4*k4+2]=a.z; w0[4*k4+3]=a.w;
        float4 bq = *(const float4*)(Wz + 4*k4);
        w1[4*k4+0]=bq.x; w1[4*k4+1]=bq.y; w1[4*k4+2]=bq.z; w1[4*k4+3]=bq.w;
        float4 c = *(const float4*)(Wn + 4*k4);
        w2[4*k4+0]=c.x; w2[4*k4+1]=c.y; w2[4*k4+2]=c.z; w2[4*k4+3]=c.w;
    }
    float b0 = bhh[j], b1 = bhh[NH + j], b2 = bhh[2*NH + j];
    int d = dur[bp];
    float hj = 0.0f;
    hs[w][j] = 0.0f;
    __syncthreads();
    const float* grow = gi + (size_t)(bp - bp0)*DM*NG;
    for (int t = 0; t < DM; ++t){
        float g0 = grow[j], g1 = grow[NH + j], g2 = grow[2*NH + j];
        grow += NG;
        float a0 = b0, a1 = b1, a2 = b2;
        #pragma unroll
        for (int k4 = 0; k4 < NH/4; ++k4){
            float4 hv = *(const float4*)&hs[w][4*k4];   // broadcast read
            a0 = fmaf(hv.x, w0[4*k4+0], a0); a1 = fmaf(hv.x, w1[4*k4+0], a1); a2 = fmaf(hv.x, w2[4*k4+0], a2);
            a0 = fmaf(hv.y, w0[4*k4+1], a0); a1 = fmaf(hv.y, w1[4*k4+1], a1); a2 = fmaf(hv.y, w2[4*k4+1], a2);
            a0 = fmaf(hv.z, w0[4*k4+2], a0); a1 = fmaf(hv.z, w1[4*k4+2], a1); a2 = fmaf(hv.z, w2[4*k4+2], a2);
            a0 = fmaf(hv.w, w0[4*k4+3], a0); a1 = fmaf(hv.w, w1[4*k4+3], a1); a2 = fmaf(hv.w, w2[4*k4+3], a2);
        }
        float r = sigm(g0 + a0);
        float z = sigm(g1 + a1);
        float n = tanh_f(g2 + r*a2);
        float hn2 = (1.0f - z)*n + z*hj;
        if (t < d) hj = hn2;        // wave-uniform predicate
        __syncthreads();
        hs[w][j] = hj;
        __syncthreads();
    }
    float msk = (d > 0) ? 1.0f : 0.0f;
    out[(size_t)bp*(2*NH) + j] = hj * msk;
}

// ---------------- K4: backward GRU single step from h=0 ---------------------
__global__ __launch_bounds__(256) void k_bwd(const float* __restrict__ mels,
                                             const int* __restrict__ starts,
                                             const int* __restrict__ dur,
                                             const float* __restrict__ Wihb,
                                             const float* __restrict__ bihb,
                                             const float* __restrict__ bhhb,
                                             const float* __restrict__ cw, const float* __restrict__ cb,
                                             const float* __restrict__ bg, const float* __restrict__ bb,
                                             const float* __restrict__ bm, const float* __restrict__ bv,
                                             float* __restrict__ out){
    __shared__ float xl[4][ND];
    int tid = threadIdx.x;
    int w = tid >> 6, j = tid & 63;
    int bp = blockIdx.x*4 + w;
    int d  = dur[bp];
    int st = starts[bp];
    Aff A = make_aff(cw,cb,bg,bb,bm,bv);
    int row = st + d - 1; row = (row < NT-1) ? row : (NT-1);
    if (j < ND/4){
        float4 v = *(const float4*)(mels + ((size_t)(bp/NP)*NT + row)*ND + j*4);
        v.x = aff(v.x, A); v.y = aff(v.y, A); v.z = aff(v.z, A); v.w = aff(v.w, A);
        *(float4*)&xl[w][j*4] = v;
    }
    __syncthreads();
    float a0 = bihb[j], a1 = bihb[NH + j], a2 = bihb[2*NH + j];
    const float* Wr = Wihb + (size_t)j*ND;
    const float* Wz = Wihb + (size_t)(NH + j)*ND;
    const float* Wn = Wihb + (size_t)(2*NH + j)*ND;
    #pragma unroll
    for (int d4 = 0; d4 < ND/4; ++d4){
        float4 xv = *(const float4*)&xl[w][4*d4];
        float4 wr = *(const float4*)(Wr + 4*d4);
        float4 wz = *(const float4*)(Wz + 4*d4);
        float4 wn = *(const float4*)(Wn + 4*d4);
        a0 = fmaf(xv.x, wr.x, a0); a0 = fmaf(xv.y, wr.y, a0); a0 = fmaf(xv.z, wr.z, a0); a0 = fmaf(xv.w, wr.w, a0);
        a1 = fmaf(xv.x, wz.x, a1); a1 = fmaf(xv.y, wz.y, a1); a1 = fmaf(xv.z, wz.z, a1); a1 = fmaf(xv.w, wz.w, a1);
        a2 = fmaf(xv.x, wn.x, a2); a2 = fmaf(xv.y, wn.y, a2); a2 = fmaf(xv.z, wn.z, a2); a2 = fmaf(xv.w, wn.w, a2);
    }
    float hr = bhhb[j], hz = bhhb[NH + j], hn = bhhb[2*NH + j];
    float r = sigm(a0 + hr);
    float z = sigm(a1 + hz);
    float n = tanh_f(a2 + r*hn);
    float hb = (1.0f - z)*n;                 // + z*0
    float msk = (d > 0) ? 1.0f : 0.0f;
    out[(size_t)bp*(2*NH) + NH + j] = hb * msk;
}

extern "C" void kernel_launch(void* const* d_in, const int* in_sizes, int n_in,
                              void* d_out, int out_size, void* d_ws, size_t ws_size,
                              hipStream_t stream){
    const float* mels = (const float*)d_in[0];
    const int*   dur  = (const int*)d_in[1];
    // d_in[2] = max_dur (compile-time constant here)
    const float* cw = (const float*)d_in[3];
    const float* cb = (const float*)d_in[4];
    const float* bg = (const float*)d_in[5];
    const float* bb = (const float*)d_in[6];
    const float* bm = (const float*)d_in[7];
    const float* bv = (const float*)d_in[8];
    const float* Wihf = (const float*)d_in[9];
    const float* Whhf = (const float*)d_in[10];
    const float* bihf = (const float*)d_in[11];
    const float* bhhf = (const float*)d_in[12];
    const float* Wihb = (const float*)d_in[13];
    // d_in[14] = W_hh_b — mathematically unused (h0 = 0 → gh = bhh_b)
    const float* bihb = (const float*)d_in[15];
    const float* bhhb = (const float*)d_in[16];
    float* out = (float*)d_out;

    int*   starts = (int*)d_ws;
    float* gi     = (float*)((char*)d_ws + 32768);
    size_t avail  = (ws_size > 32768) ? ws_size - 32768 : 0;
    size_t per_bp = (size_t)DM*NG*sizeof(float);   // 36864 B per sequence

    // pick largest chunk (divisor of 6144, multiple of 8) that fits in ws
    static const int copts[] = {6144,3072,2048,1536,1024,768,512,384,256,192,128,96,64,48,32,24,16,8};
    int chunk = 8;
    for (int i = 0; i < 18; ++i){
        if ((size_t)copts[i]*per_bp <= avail){ chunk = copts[i]; break; }
    }

    k_starts<<<NB, NP, 0, stream>>>(dur, starts);
    for (int bp0 = 0; bp0 < NBP; bp0 += chunk){
        k_gi<<<chunk, 192, 0, stream>>>(mels, starts, Wihf, bihf,
                                        cw, cb, bg, bb, bm, bv, gi, bp0);
        k_gru<<<chunk/8, 512, 0, stream>>>(gi, Whhf, bhhf, dur, out, bp0);
    }
    k_bwd<<<NBP/4, 256, 0, stream>>>(mels, starts, dur, Wihb, bihb, bhhb,
                                     cw, cb, bg, bb, bm, bv, out);
}

// Round 3
// 304.540 us; speedup vs baseline: 2.0147x; 2.0147x over previous
//
#include <hip/hip_runtime.h>

#define NB 32
#define NP 192
#define DM 48          // max_dur
#define ND 80          // DMEL
#define NH 64          // H
#define NT (NP*DM)     // 9216
#define NBP (NB*NP)    // 6144
#define NG (3*NH)      // 192
#define NSG (NBP/16)   // 384 groups of 16 sequences

typedef _Float16 half8 __attribute__((ext_vector_type(8)));
typedef float f32x4 __attribute__((ext_vector_type(4)));

// workspace layout (bytes)
#define WS_STARTS 0
#define WS_WIH  32768                     // 12 frag x 3 ks x 64 lane x 8 f16 = 36864 B
#define WS_WHH  (32768 + 36864)           // 12 frag x 2 ks x 64 lane x 8 f16 = 24576 B
#define WS_GI   98304                     // NSG x 48 x 12 x 64 x 8 B = 113,246,208 B

__device__ __forceinline__ float sigm(float x){ return 1.0f/(1.0f + __expf(-x)); }
__device__ __forceinline__ float tanh_f(float x){ return 1.0f - 2.0f/(1.0f + __expf(2.0f*x)); }

__device__ __forceinline__ unsigned packh2(float a, float b){
    unsigned short ua = __builtin_bit_cast(unsigned short, (_Float16)a);
    unsigned short ub = __builtin_bit_cast(unsigned short, (_Float16)b);
    return (unsigned)ua | ((unsigned)ub << 16);
}
__device__ __forceinline__ float unpackh(unsigned w, int hi){
    unsigned short u = (unsigned short)(hi ? (w >> 16) : (w & 0xffffu));
    return (float)__builtin_bit_cast(_Float16, u);
}

struct Aff { float a0,c0,a1,c1; };
__device__ __forceinline__ Aff make_aff(const float* cw, const float* cb, const float* bg,
                                        const float* bb, const float* bm, const float* bv){
    float s0 = bg[0]*rsqrtf(bv[0]+1e-5f);
    float s1 = bg[1]*rsqrtf(bv[1]+1e-5f);
    Aff A;
    A.a0 = cw[0]*s0; A.c0 = (cb[0]-bm[0])*s0 + bb[0];
    A.a1 = cw[1]*s1; A.c1 = (cb[1]-bm[1])*s1 + bb[1];
    return A;
}
__device__ __forceinline__ float aff(float x, const Aff A){
    float y = fmaxf(fmaf(A.a0, x, A.c0), 0.0f);
    return fmaxf(fmaf(A.a1, y, A.c1), 0.0f);
}

// ---------------- K1: exclusive cumsum of durations -> starts ----------------
__global__ __launch_bounds__(NP) void k_starts(const int* __restrict__ dur,
                                               int* __restrict__ starts){
    __shared__ int s[NP];
    int b = blockIdx.x, p = threadIdx.x;
    int d = dur[b*NP + p];
    s[p] = d;
    __syncthreads();
    #pragma unroll
    for (int off = 1; off < NP; off <<= 1){
        int v = (p >= off) ? s[p - off] : 0;
        __syncthreads();
        s[p] += v;
        __syncthreads();
    }
    starts[b*NP + p] = s[p] - d;   // exclusive
}

// ---------------- K_prep: convert weights to f16 MFMA A-fragment layout -----
// Frag mapping (16x16x32): A value at lane l, slot (ks,i): W[j][k],
//   j = gate*64 + w*16 + (l&15),  k = ks*32 + (l>>4)*8 + i, frag id f = gate*4+w
__global__ __launch_bounds__(256) void k_prep(const float* __restrict__ Wih,
                                              const float* __restrict__ Whh,
                                              unsigned short* __restrict__ wih16,
                                              unsigned short* __restrict__ whh16){
    int idx = blockIdx.x*256 + threadIdx.x;
    if (idx < 12*3*64*8){
        int i = idx & 7, l = (idx>>3) & 63, ks = (idx>>9) % 3, f = idx / 1536;
        int j = (f>>2)*64 + (f&3)*16 + (l&15);
        int k = ks*32 + (l>>4)*8 + i;
        float v = (k < ND) ? Wih[j*ND + k] : 0.0f;
        wih16[idx] = __builtin_bit_cast(unsigned short, (_Float16)v);
    } else {
        int idx2 = idx - 12*3*64*8;
        if (idx2 < 12*2*64*8){
            int i = idx2 & 7, l = (idx2>>3) & 63, ks = (idx2>>9) & 1, f = idx2 / 1024;
            int j = (f>>2)*64 + (f&3)*16 + (l&15);
            int k = ks*32 + (l>>4)*8 + i;
            whh16[idx2] = __builtin_bit_cast(unsigned short, (_Float16)Whh[j*NH + k]);
        }
    }
}

// ---------------- K2: gi = W_ih x + b_ih via MFMA, f16-split x --------------
// Block: 16 sequences (sg), 256 threads / 4 waves. Wave w owns j-rows
// {g*64 + w*16 .. +15} for g=r,z,n. Per t: GEMM (192x96)x(96x16).
// Output layout: gi[((sg*48+t)*12 + gate*4+w)*64 + lane] as uint2 (4 f16).
__global__ __launch_bounds__(256) void k_gi2(const float* __restrict__ mels,
                                             const int* __restrict__ starts,
                                             const unsigned short* __restrict__ wih16,
                                             const float* __restrict__ bih,
                                             const float* __restrict__ cw, const float* __restrict__ cb,
                                             const float* __restrict__ bg, const float* __restrict__ bb,
                                             const float* __restrict__ bm, const float* __restrict__ bv,
                                             uint2* __restrict__ gi){
    __shared__ alignas(16) unsigned short xh[16][104];  // x hi-f16, [seq][k], k padded 96->104
    __shared__ alignas(16) unsigned short xl[16][104];  // x lo-f16
    int sg  = blockIdx.x;
    int tid = threadIdx.x;
    int w = tid >> 6, l = tid & 63;
    int sc = l & 15, g4 = l >> 4;
    int b = sg / 12;                       // 12 seq-groups per batch row
    Aff A = make_aff(cw,cb,bg,bb,bm,bv);

    // A fragments (held in VGPRs whole kernel): 3 gates x 3 ksteps
    half8 Af[3][3];
    #pragma unroll
    for (int gt = 0; gt < 3; ++gt)
        #pragma unroll
        for (int ks = 0; ks < 3; ++ks)
            Af[gt][ks] = *(const half8*)(wih16 + (size_t)(((gt*4+w)*3 + ks)*64 + l)*8);
    // bias in D-layout: row = g4*4 + r
    f32x4 bi[3];
    #pragma unroll
    for (int gt = 0; gt < 3; ++gt){
        float4 t4 = *(const float4*)(bih + gt*64 + w*16 + g4*4);
        bi[gt][0]=t4.x; bi[gt][1]=t4.y; bi[gt][2]=t4.z; bi[gt][3]=t4.w;
    }

    // staging assignment: 320 float4-units (16 seq x 20), unit u -> (seq u/20, k-quad u%20)
    int u0 = tid;            int s0 = u0/20, q0 = u0%20;
    int st0 = starts[sg*16 + s0];
    bool has1 = (tid < 64);
    int u1 = tid + 256;      int s1 = u1/20, q1 = u1%20;
    int st1 = has1 ? starts[sg*16 + s1] : 0;
    const float* mb = mels + (size_t)b*NT*ND;

    // zero the K-pad region 80..95 once (never overwritten)
    if (tid < 64){
        int s = tid >> 2, c = tid & 3;
        *(uint2*)&xh[s][80 + 4*c] = uint2{0u,0u};
        *(uint2*)&xl[s][80 + 4*c] = uint2{0u,0u};
    }

    // preload t=0
    int r0i = st0;       r0i = (r0i < NT-1) ? r0i : (NT-1);
    float4 r0 = *(const float4*)(mb + (size_t)r0i*ND + 4*q0);
    float4 r1 = {0,0,0,0};
    if (has1){ int r1i = st1; r1i = (r1i < NT-1) ? r1i : (NT-1);
               r1 = *(const float4*)(mb + (size_t)r1i*ND + 4*q1); }

    uint2* gout = gi + (size_t)sg*48*12*64;
    for (int t = 0; t < DM; ++t){
        // ---- write staged x (affine+relu+split) to LDS
        {
            float y0=aff(r0.x,A), y1=aff(r0.y,A), y2=aff(r0.z,A), y3=aff(r0.w,A);
            float p0=(float)(_Float16)y0, p1=(float)(_Float16)y1, p2=(float)(_Float16)y2, p3=(float)(_Float16)y3;
            *(uint2*)&xh[s0][4*q0] = uint2{packh2(y0,y1), packh2(y2,y3)};
            *(uint2*)&xl[s0][4*q0] = uint2{packh2(y0-p0,y1-p1), packh2(y2-p2,y3-p3)};
            if (has1){
                float z0=aff(r1.x,A), z1=aff(r1.y,A), z2=aff(r1.z,A), z3=aff(r1.w,A);
                float w0=(float)(_Float16)z0, w1=(float)(_Float16)z1, w2=(float)(_Float16)z2, w3=(float)(_Float16)z3;
                *(uint2*)&xh[s1][4*q1] = uint2{packh2(z0,z1), packh2(z2,z3)};
                *(uint2*)&xl[s1][4*q1] = uint2{packh2(z0-w0,z1-w1), packh2(z2-w2,z3-w3)};
            }
        }
        __syncthreads();
        // ---- prefetch next t's x into regs (hides HBM latency under MFMA)
        {
            int tn = (t+1 < DM) ? t+1 : t;
            int a0 = st0 + tn; a0 = (a0 < NT-1) ? a0 : (NT-1);
            r0 = *(const float4*)(mb + (size_t)a0*ND + 4*q0);
            if (has1){ int a1 = st1 + tn; a1 = (a1 < NT-1) ? a1 : (NT-1);
                       r1 = *(const float4*)(mb + (size_t)a1*ND + 4*q1); }
        }
        // ---- MFMA: acc = bias + W*(x_hi + x_lo)
        f32x4 acc[3];
        #pragma unroll
        for (int gt = 0; gt < 3; ++gt) acc[gt] = bi[gt];
        #pragma unroll
        for (int ks = 0; ks < 3; ++ks){
            half8 Bh = *(const half8*)&xh[sc][ks*32 + g4*8];
            half8 Bl = *(const half8*)&xl[sc][ks*32 + g4*8];
            #pragma unroll
            for (int gt = 0; gt < 3; ++gt){
                acc[gt] = __builtin_amdgcn_mfma_f32_16x16x32_f16(Af[gt][ks], Bh, acc[gt], 0, 0, 0);
                acc[gt] = __builtin_amdgcn_mfma_f32_16x16x32_f16(Af[gt][ks], Bl, acc[gt], 0, 0, 0);
            }
        }
        // ---- store gi as f16 pairs in frag layout
        #pragma unroll
        for (int gt = 0; gt < 3; ++gt){
            uint2 o = uint2{packh2(acc[gt][0], acc[gt][1]), packh2(acc[gt][2], acc[gt][3])};
            gout[((size_t)t*12 + gt*4 + w)*64 + l] = o;
        }
        __syncthreads();
    }
}

// ---------------- K3: batched GRU recurrence via MFMA -----------------------
// Block: 16 sequences, 4 waves; wave w owns j in [w*16, w*16+16) for all 3 gates.
// Per step: gh(48x16 per wave) = Whh_f16 * (h_hi + h_lo), gates lane-local.
__global__ __launch_bounds__(256) void k_gru2(const uint2* __restrict__ gi,
                                              const unsigned short* __restrict__ whh16,
                                              const float* __restrict__ bhh,
                                              const int* __restrict__ dur,
                                              float* __restrict__ out){
    __shared__ alignas(16) unsigned short hh[16][72];   // h hi-f16 [seq][j-dim] (pad 64->72)
    __shared__ alignas(16) unsigned short hl[16][72];   // h lo-f16
    int sg  = blockIdx.x;
    int tid = threadIdx.x;
    int w = tid >> 6, l = tid & 63;
    int sc = l & 15, g4 = l >> 4;

    half8 Af[3][2];
    #pragma unroll
    for (int gt = 0; gt < 3; ++gt)
        #pragma unroll
        for (int ks = 0; ks < 2; ++ks)
            Af[gt][ks] = *(const half8*)(whh16 + (size_t)(((gt*4+w)*2 + ks)*64 + l)*8);
    f32x4 bh[3];
    #pragma unroll
    for (int gt = 0; gt < 3; ++gt){
        float4 t4 = *(const float4*)(bhh + gt*64 + w*16 + g4*4);
        bh[gt][0]=t4.x; bh[gt][1]=t4.y; bh[gt][2]=t4.z; bh[gt][3]=t4.w;
    }
    int dl = dur[sg*16 + sc];
    float h[4] = {0.f, 0.f, 0.f, 0.f};

    const uint2* gbase = gi + (size_t)sg*48*12*64;
    uint2 c0[3], c1[3];
    #pragma unroll
    for (int gt = 0; gt < 3; ++gt) c0[gt] = gbase[(size_t)(gt*4 + w)*64 + l];

    auto step = [&](int t, uint2 (&cur)[3], uint2 (&nxt)[3]){
        // publish h (hi/lo f16) for the exchange
        float q0 = h[0]-(float)(_Float16)h[0], q1 = h[1]-(float)(_Float16)h[1];
        float q2 = h[2]-(float)(_Float16)h[2], q3 = h[3]-(float)(_Float16)h[3];
        *(uint2*)&hh[sc][w*16 + g4*4] = uint2{packh2(h[0],h[1]), packh2(h[2],h[3])};
        *(uint2*)&hl[sc][w*16 + g4*4] = uint2{packh2(q0,q1), packh2(q2,q3)};
        __syncthreads();
        half8 Bh0 = *(const half8*)&hh[sc][g4*8];
        half8 Bh1 = *(const half8*)&hh[sc][32 + g4*8];
        half8 Bl0 = *(const half8*)&hl[sc][g4*8];
        half8 Bl1 = *(const half8*)&hl[sc][32 + g4*8];
        __syncthreads();   // reads done; next iteration may overwrite
        // prefetch next step's gi
        int tn = (t+1 < DM) ? t+1 : t;
        #pragma unroll
        for (int gt = 0; gt < 3; ++gt) nxt[gt] = gbase[((size_t)tn*12 + gt*4 + w)*64 + l];
        // gh = Whh * (h_hi + h_lo)
        f32x4 zero = {0.f,0.f,0.f,0.f};
        f32x4 acc[3];
        #pragma unroll
        for (int gt = 0; gt < 3; ++gt) acc[gt] = zero;
        #pragma unroll
        for (int gt = 0; gt < 3; ++gt){
            acc[gt] = __builtin_amdgcn_mfma_f32_16x16x32_f16(Af[gt][0], Bh0, acc[gt], 0, 0, 0);
            acc[gt] = __builtin_amdgcn_mfma_f32_16x16x32_f16(Af[gt][0], Bl0, acc[gt], 0, 0, 0);
            acc[gt] = __builtin_amdgcn_mfma_f32_16x16x32_f16(Af[gt][1], Bh1, acc[gt], 0, 0, 0);
            acc[gt] = __builtin_amdgcn_mfma_f32_16x16x32_f16(Af[gt][1], Bl1, acc[gt], 0, 0, 0);
        }
        // gates (lane-local; D row = g4*4 + r, col = sc)
        #pragma unroll
        for (int r = 0; r < 4; ++r){
            unsigned wr = (r < 2) ? cur[0].x : cur[0].y;
            unsigned wz = (r < 2) ? cur[1].x : cur[1].y;
            unsigned wn = (r < 2) ? cur[2].x : cur[2].y;
            float gr = unpackh(wr, r & 1);
            float gz = unpackh(wz, r & 1);
            float gn = unpackh(wn, r & 1);
            float rr = sigm(gr + acc[0][r] + bh[0][r]);
            float zz = sigm(gz + acc[1][r] + bh[1][r]);
            float nn = tanh_f(gn + rr*(acc[2][r] + bh[2][r]));
            float hn2 = (1.0f - zz)*nn + zz*h[r];
            h[r] = (t < dl) ? hn2 : h[r];
        }
    };
    for (int t = 0; t < DM; t += 2){ step(t, c0, c1); step(t+1, c1, c0); }

    float msk = (dl > 0) ? 1.0f : 0.0f;
    float4 o4 = {h[0]*msk, h[1]*msk, h[2]*msk, h[3]*msk};
    *(float4*)(out + ((size_t)sg*16 + sc)*(2*NH) + w*16 + g4*4) = o4;
}

// ---------------- K4: backward GRU single step from h=0 (fp32) --------------
__global__ __launch_bounds__(256) void k_bwd(const float* __restrict__ mels,
                                             const int* __restrict__ starts,
                                             const int* __restrict__ dur,
                                             const float* __restrict__ Wihb,
                                             const float* __restrict__ bihb,
                                             const float* __restrict__ bhhb,
                                             const float* __restrict__ cw, const float* __restrict__ cb,
                                             const float* __restrict__ bg, const float* __restrict__ bb,
                                             const float* __restrict__ bm, const float* __restrict__ bv,
                                             float* __restrict__ out){
    __shared__ float xl[4][ND];
    int tid = threadIdx.x;
    int w = tid >> 6, j = tid & 63;
    int bp = blockIdx.x*4 + w;
    int d  = dur[bp];
    int st = starts[bp];
    Aff A = make_aff(cw,cb,bg,bb,bm,bv);
    int row = st + d - 1; row = (row < NT-1) ? row : (NT-1);
    if (j < ND/4){
        float4 v = *(const float4*)(mels + ((size_t)(bp/NP)*NT + row)*ND + j*4);
        v.x = aff(v.x, A); v.y = aff(v.y, A); v.z = aff(v.z, A); v.w = aff(v.w, A);
        *(float4*)&xl[w][j*4] = v;
    }
    __syncthreads();
    float a0 = bihb[j], a1 = bihb[NH + j], a2 = bihb[2*NH + j];
    const float* Wr = Wihb + (size_t)j*ND;
    const float* Wz = Wihb + (size_t)(NH + j)*ND;
    const float* Wn = Wihb + (size_t)(2*NH + j)*ND;
    #pragma unroll
    for (int d4 = 0; d4 < ND/4; ++d4){
        float4 xv = *(const float4*)&xl[w][4*d4];
        float4 wr = *(const float4*)(Wr + 4*d4);
        float4 wz = *(const float4*)(Wz + 4*d4);
        float4 wn = *(const float4*)(Wn + 4*d4);
        a0 = fmaf(xv.x, wr.x, a0); a0 = fmaf(xv.y, wr.y, a0); a0 = fmaf(xv.z, wr.z, a0); a0 = fmaf(xv.w, wr.w, a0);
        a1 = fmaf(xv.x, wz.x, a1); a1 = fmaf(xv.y, wz.y, a1); a1 = fmaf(xv.z, wz.z, a1); a1 = fmaf(xv.w, wz.w, a1);
        a2 = fmaf(xv.x, wn.x, a2); a2 = fmaf(xv.y, wn.y, a2); a2 = fmaf(xv.z, wn.z, a2); a2 = fmaf(xv.w, wn.w, a2);
    }
    float hr = bhhb[j], hz = bhhb[NH + j], hn = bhhb[2*NH + j];
    float r = sigm(a0 + hr);
    float z = sigm(a1 + hz);
    float n = tanh_f(a2 + r*hn);
    float hb = (1.0f - z)*n;                 // + z*0
    float msk = (d > 0) ? 1.0f : 0.0f;
    out[(size_t)bp*(2*NH) + NH + j] = hb * msk;
}

extern "C" void kernel_launch(void* const* d_in, const int* in_sizes, int n_in,
                              void* d_out, int out_size, void* d_ws, size_t ws_size,
                              hipStream_t stream){
    const float* mels = (const float*)d_in[0];
    const int*   dur  = (const int*)d_in[1];
    const float* cw = (const float*)d_in[3];
    const float* cb = (const float*)d_in[4];
    const float* bg = (const float*)d_in[5];
    const float* bb = (const float*)d_in[6];
    const float* bm = (const float*)d_in[7];
    const float* bv = (const float*)d_in[8];
    const float* Wihf = (const float*)d_in[9];
    const float* Whhf = (const float*)d_in[10];
    const float* bihf = (const float*)d_in[11];
    const float* bhhf = (const float*)d_in[12];
    const float* Wihb = (const float*)d_in[13];
    // d_in[14] = W_hh_b — unused (h0 = 0 => gh = bhh_b)
    const float* bihb = (const float*)d_in[15];
    const float* bhhb = (const float*)d_in[16];
    float* out = (float*)d_out;

    int*            starts = (int*)((char*)d_ws + WS_STARTS);
    unsigned short* wih16  = (unsigned short*)((char*)d_ws + WS_WIH);
    unsigned short* whh16  = (unsigned short*)((char*)d_ws + WS_WHH);
    uint2*          gi     = (uint2*)((char*)d_ws + WS_GI);

    k_starts<<<NB, NP, 0, stream>>>(dur, starts);
    k_prep<<<120, 256, 0, stream>>>(Wihf, Whhf, wih16, whh16);
    k_gi2<<<NSG, 256, 0, stream>>>(mels, starts, wih16, bihf,
                                   cw, cb, bg, bb, bm, bv, gi);
    k_gru2<<<NSG, 256, 0, stream>>>(gi, whh16, bhhf, dur, out);
    k_bwd<<<NBP/4, 256, 0, stream>>>(mels, starts, dur, Wihb, bihb, bhhb,
                                     cw, cb, bg, bb, bm, bv, out);
}

// Round 4
// 244.952 us; speedup vs baseline: 2.5048x; 1.2433x over previous
//
#include <hip/hip_runtime.h>

#define NB 32
#define NP 192
#define DM 48          // max_dur
#define ND 80          // DMEL
#define NH 64          // H
#define NT (NP*DM)     // 9216
#define NBP (NB*NP)    // 6144
#define NSG (NBP/16)   // 384 blocks of 16 sequences

typedef _Float16 half8 __attribute__((ext_vector_type(8)));
typedef float f32x4 __attribute__((ext_vector_type(4)));

// workspace layout (bytes)
#define WS_STARTS 0                        // 6144 ints = 24576 B
#define WS_WIH   32768                     // 12 frag x 3 ks x 64 lane x 8 f16 = 36864 B
#define WS_WHH   (32768 + 36864)           // 12 frag x 2 ks x 64 lane x 8 f16 = 24576 B
#define WS_WIHB  (32768 + 36864 + 24576)   // 36864 B

__device__ __forceinline__ float sigm(float x){ return 1.0f/(1.0f + __expf(-x)); }
__device__ __forceinline__ float tanh_f(float x){ return 1.0f - 2.0f/(1.0f + __expf(2.0f*x)); }

__device__ __forceinline__ unsigned packh2(float a, float b){
    unsigned short ua = __builtin_bit_cast(unsigned short, (_Float16)a);
    unsigned short ub = __builtin_bit_cast(unsigned short, (_Float16)b);
    return (unsigned)ua | ((unsigned)ub << 16);
}

struct Aff { float a0,c0,a1,c1; };
__device__ __forceinline__ Aff make_aff(const float* cw, const float* cb, const float* bg,
                                        const float* bb, const float* bm, const float* bv){
    float s0 = bg[0]*rsqrtf(bv[0]+1e-5f);
    float s1 = bg[1]*rsqrtf(bv[1]+1e-5f);
    Aff A;
    A.a0 = cw[0]*s0; A.c0 = (cb[0]-bm[0])*s0 + bb[0];
    A.a1 = cw[1]*s1; A.c1 = (cb[1]-bm[1])*s1 + bb[1];
    return A;
}
__device__ __forceinline__ float aff(float x, const Aff A){
    float y = fmaxf(fmaf(A.a0, x, A.c0), 0.0f);
    return fmaxf(fmaf(A.a1, y, A.c1), 0.0f);
}

// ---------------- K1: exclusive cumsum of durations -> starts ----------------
__global__ __launch_bounds__(NP) void k_starts(const int* __restrict__ dur,
                                               int* __restrict__ starts){
    __shared__ int s[NP];
    int b = blockIdx.x, p = threadIdx.x;
    int d = dur[b*NP + p];
    s[p] = d;
    __syncthreads();
    #pragma unroll
    for (int off = 1; off < NP; off <<= 1){
        int v = (p >= off) ? s[p - off] : 0;
        __syncthreads();
        s[p] += v;
        __syncthreads();
    }
    starts[b*NP + p] = s[p] - d;   // exclusive
}

// ---------------- K_prep: f16 MFMA A-fragment layout for Wih_f, Whh_f, Wih_b
// A value at lane l, slot (ks,i): W[j][k], j = (f>>2)*64 + (f&3)*16 + (l&15),
// k = ks*32 + (l>>4)*8 + i   (f = gate*4 + wave)
__global__ __launch_bounds__(256) void k_prep(const float* __restrict__ Wih,
                                              const float* __restrict__ Whh,
                                              const float* __restrict__ Wihb,
                                              unsigned short* __restrict__ wih16,
                                              unsigned short* __restrict__ whh16,
                                              unsigned short* __restrict__ wihb16){
    int idx = blockIdx.x*256 + threadIdx.x;
    if (idx < 12*3*64*8){
        int i = idx & 7, l = (idx>>3) & 63, ks = (idx>>9) % 3, f = idx / 1536;
        int j = (f>>2)*64 + (f&3)*16 + (l&15);
        int k = ks*32 + (l>>4)*8 + i;
        float v = (k < ND) ? Wih[j*ND + k] : 0.0f;
        wih16[idx] = __builtin_bit_cast(unsigned short, (_Float16)v);
        return;
    }
    int idx2 = idx - 12*3*64*8;
    if (idx2 < 12*2*64*8){
        int i = idx2 & 7, l = (idx2>>3) & 63, ks = (idx2>>9) & 1, f = idx2 / 1024;
        int j = (f>>2)*64 + (f&3)*16 + (l&15);
        int k = ks*32 + (l>>4)*8 + i;
        whh16[idx2] = __builtin_bit_cast(unsigned short, (_Float16)Whh[j*NH + k]);
        return;
    }
    int idx3 = idx2 - 12*2*64*8;
    if (idx3 < 12*3*64*8){
        int i = idx3 & 7, l = (idx3>>3) & 63, ks = (idx3>>9) % 3, f = idx3 / 1536;
        int j = (f>>2)*64 + (f&3)*16 + (l&15);
        int k = ks*32 + (l>>4)*8 + i;
        float v = (k < ND) ? Wihb[j*ND + k] : 0.0f;
        wihb16[idx3] = __builtin_bit_cast(unsigned short, (_Float16)v);
    }
}

// ---------------- K_fused: gather+affine + gi MFMA + GRU recurrence + bwd ----
// Block: 16 seqs, 4 waves. Per step t: stage x(t+1), prefetch x(t+2),
// gi = Wih*(xh+xl) (18 MFMA), gh = Whh*(hh+hl) (12 MFMA), lane-local gates.
// 1 barrier/step via x triple-buffer + h double-buffer.
__global__ __launch_bounds__(256, 2) void k_fused(
        const float* __restrict__ mels,
        const int* __restrict__ starts,
        const int* __restrict__ dur,
        const unsigned short* __restrict__ wih16,
        const unsigned short* __restrict__ whh16,
        const unsigned short* __restrict__ wihb16,
        const float* __restrict__ bih,  const float* __restrict__ bhh,
        const float* __restrict__ bihb, const float* __restrict__ bhhb,
        const float* __restrict__ cw, const float* __restrict__ cb,
        const float* __restrict__ bg, const float* __restrict__ bb,
        const float* __restrict__ bm, const float* __restrict__ bv,
        float* __restrict__ out){
    __shared__ alignas(16) unsigned short xh3[3*16*104];
    __shared__ alignas(16) unsigned short xl3[3*16*104];
    __shared__ alignas(16) unsigned short hh2[2*16*72];
    __shared__ alignas(16) unsigned short hl2[2*16*72];
    __shared__ alignas(16) float xlast[16*100];

    int sg  = blockIdx.x;
    int tid = threadIdx.x;
    int w = tid >> 6, l = tid & 63;
    int sc = l & 15, g4 = l >> 4;
    int b = sg / 12;
    Aff A = make_aff(cw,cb,bg,bb,bm,bv);

    // A fragments: Wih (3 gates x 3 ks), Whh (3 gates x 2 ks)
    half8 Af[3][3], Ah[3][2];
    #pragma unroll
    for (int gt = 0; gt < 3; ++gt){
        #pragma unroll
        for (int ks = 0; ks < 3; ++ks)
            Af[gt][ks] = *(const half8*)(wih16 + (size_t)(((gt*4+w)*3 + ks)*64 + l)*8);
        #pragma unroll
        for (int ks = 0; ks < 2; ++ks)
            Ah[gt][ks] = *(const half8*)(whh16 + (size_t)(((gt*4+w)*2 + ks)*64 + l)*8);
    }
    f32x4 bi[3], bh[3];
    #pragma unroll
    for (int gt = 0; gt < 3; ++gt){
        float4 t4 = *(const float4*)(bih + gt*64 + w*16 + g4*4);
        bi[gt][0]=t4.x; bi[gt][1]=t4.y; bi[gt][2]=t4.z; bi[gt][3]=t4.w;
        float4 u4 = *(const float4*)(bhh + gt*64 + w*16 + g4*4);
        bh[gt][0]=u4.x; bh[gt][1]=u4.y; bh[gt][2]=u4.z; bh[gt][3]=u4.w;
    }
    int dl_g = dur[sg*16 + sc];

    // staging: 320 float4-units (16 seq x 20 quads); unit u -> (u/20, u%20)
    int s0 = tid/20, q0 = tid%20;
    bool has1 = ((tid & 3) == 0);
    int u1 = 256 + (tid >> 2);
    int s1 = u1/20, q1 = u1%20;
    int st0 = starts[sg*16 + s0], dl0 = dur[sg*16 + s0];
    int st1 = 0, dl1 = 0;
    if (has1){ st1 = starts[sg*16 + s1]; dl1 = dur[sg*16 + s1]; }
    const float* mb = mels + (size_t)b*NT*ND;

    auto ldx = [&](int st, int t, int q) -> float4 {
        int r = st + t; r = (r < NT-1) ? r : (NT-1);
        return *(const float4*)(mb + (size_t)r*ND + 4*q);
    };
    auto wrx = [&](int pw, int s, int q, float4 v, bool islast){
        float y0=aff(v.x,A), y1=aff(v.y,A), y2=aff(v.z,A), y3=aff(v.w,A);
        float p0=(float)(_Float16)y0, p1=(float)(_Float16)y1;
        float p2=(float)(_Float16)y2, p3=(float)(_Float16)y3;
        *(uint2*)&xh3[(pw*16+s)*104 + 4*q] = uint2{packh2(y0,y1), packh2(y2,y3)};
        *(uint2*)&xl3[(pw*16+s)*104 + 4*q] = uint2{packh2(y0-p0,y1-p1), packh2(y2-p2,y3-p3)};
        if (islast) *(float4*)&xlast[s*100 + 4*q] = make_float4(y0,y1,y2,y3);
    };

    // ---- preloop zeroing: x K-pad (cols 80..95, 3 bufs), xlast pad, h0 bufs
    for (int i = tid; i < 48; i += 256){          // 3 bufs x 16 seqs
        int bf = i/16, s = i%16;
        *(uint4*)&xh3[(bf*16+s)*104 + 80] = uint4{0,0,0,0};
        *(uint4*)&xh3[(bf*16+s)*104 + 88] = uint4{0,0,0,0};
        *(uint4*)&xl3[(bf*16+s)*104 + 80] = uint4{0,0,0,0};
        *(uint4*)&xl3[(bf*16+s)*104 + 88] = uint4{0,0,0,0};
    }
    for (int i = tid; i < 80; i += 256){          // xlast cols 80..99
        int s = i/5, c = i%5;
        *(float4*)&xlast[s*100 + 80 + 4*c] = make_float4(0,0,0,0);
    }
    for (int i = tid; i < 144; i += 256){         // h buffer 0 = 0
        int s = i/9, u = i%9;
        *(uint4*)&hh2[s*72 + u*8] = uint4{0,0,0,0};
        *(uint4*)&hl2[s*72 + u*8] = uint4{0,0,0,0};
    }

    // ---- preload: write x(0) to buf 0, load x(1) into set0
    {
        float4 v0 = ldx(st0, 0, q0);
        wrx(0, s0, q0, v0, (0 == dl0-1));
        if (has1){ float4 v1 = ldx(st1, 0, q1); wrx(0, s1, q1, v1, (0 == dl1-1)); }
    }
    float4 r0a = ldx(st0, 1, q0);
    float4 r0b = {0,0,0,0};
    if (has1) r0b = ldx(st1, 1, q1);
    float4 r1a = {0,0,0,0}, r1b = {0,0,0,0};
    float h[4] = {0.f,0.f,0.f,0.f};
    __syncthreads();

#define GSTEP(K, WA, WB, LA, LB)                                                      \
{                                                                                     \
    const int PR = (K) % 3, PW = ((K)+1) % 3, HB = (K) & 1;                           \
    int t = tb + (K);                                                                 \
    half8 Xh0 = *(const half8*)&xh3[(PR*16+sc)*104 +  0 + g4*8];                      \
    half8 Xh1 = *(const half8*)&xh3[(PR*16+sc)*104 + 32 + g4*8];                      \
    half8 Xh2 = *(const half8*)&xh3[(PR*16+sc)*104 + 64 + g4*8];                      \
    half8 Xl0 = *(const half8*)&xl3[(PR*16+sc)*104 +  0 + g4*8];                      \
    half8 Xl1 = *(const half8*)&xl3[(PR*16+sc)*104 + 32 + g4*8];                      \
    half8 Xl2 = *(const half8*)&xl3[(PR*16+sc)*104 + 64 + g4*8];                      \
    half8 Hh0 = *(const half8*)&hh2[(HB*16+sc)*72 +  0 + g4*8];                       \
    half8 Hh1 = *(const half8*)&hh2[(HB*16+sc)*72 + 32 + g4*8];                       \
    half8 Hl0 = *(const half8*)&hl2[(HB*16+sc)*72 +  0 + g4*8];                       \
    half8 Hl1 = *(const half8*)&hl2[(HB*16+sc)*72 + 32 + g4*8];                       \
    if (t+1 < DM){                                                                    \
        wrx(PW, s0, q0, WA, (t+1) == (dl0-1));                                        \
        if (has1) wrx(PW, s1, q1, WB, (t+1) == (dl1-1));                              \
    }                                                                                 \
    { int tn = (t+2 < DM) ? t+2 : DM-1;                                               \
      LA = ldx(st0, tn, q0);                                                          \
      if (has1) LB = ldx(st1, tn, q1); }                                              \
    f32x4 ga0 = bi[0], ga1 = bi[1], ga2 = bi[2];                                      \
    f32x4 ha0 = bh[0], ha1 = bh[1], ha2 = bh[2];                                      \
    ga0 = __builtin_amdgcn_mfma_f32_16x16x32_f16(Af[0][0], Xh0, ga0, 0,0,0);          \
    ga1 = __builtin_amdgcn_mfma_f32_16x16x32_f16(Af[1][0], Xh0, ga1, 0,0,0);          \
    ga2 = __builtin_amdgcn_mfma_f32_16x16x32_f16(Af[2][0], Xh0, ga2, 0,0,0);          \
    ha0 = __builtin_amdgcn_mfma_f32_16x16x32_f16(Ah[0][0], Hh0, ha0, 0,0,0);          \
    ha1 = __builtin_amdgcn_mfma_f32_16x16x32_f16(Ah[1][0], Hh0, ha1, 0,0,0);          \
    ha2 = __builtin_amdgcn_mfma_f32_16x16x32_f16(Ah[2][0], Hh0, ha2, 0,0,0);          \
    ga0 = __builtin_amdgcn_mfma_f32_16x16x32_f16(Af[0][0], Xl0, ga0, 0,0,0);          \
    ga1 = __builtin_amdgcn_mfma_f32_16x16x32_f16(Af[1][0], Xl0, ga1, 0,0,0);          \
    ga2 = __builtin_amdgcn_mfma_f32_16x16x32_f16(Af[2][0], Xl0, ga2, 0,0,0);          \
    ha0 = __builtin_amdgcn_mfma_f32_16x16x32_f16(Ah[0][0], Hl0, ha0, 0,0,0);          \
    ha1 = __builtin_amdgcn_mfma_f32_16x16x32_f16(Ah[1][0], Hl0, ha1, 0,0,0);          \
    ha2 = __builtin_amdgcn_mfma_f32_16x16x32_f16(Ah[2][0], Hl0, ha2, 0,0,0);          \
    ga0 = __builtin_amdgcn_mfma_f32_16x16x32_f16(Af[0][1], Xh1, ga0, 0,0,0);          \
    ga1 = __builtin_amdgcn_mfma_f32_16x16x32_f16(Af[1][1], Xh1, ga1, 0,0,0);          \
    ga2 = __builtin_amdgcn_mfma_f32_16x16x32_f16(Af[2][1], Xh1, ga2, 0,0,0);          \
    ha0 = __builtin_amdgcn_mfma_f32_16x16x32_f16(Ah[0][1], Hh1, ha0, 0,0,0);          \
    ha1 = __builtin_amdgcn_mfma_f32_16x16x32_f16(Ah[1][1], Hh1, ha1, 0,0,0);          \
    ha2 = __builtin_amdgcn_mfma_f32_16x16x32_f16(Ah[2][1], Hh1, ha2, 0,0,0);          \
    ga0 = __builtin_amdgcn_mfma_f32_16x16x32_f16(Af[0][1], Xl1, ga0, 0,0,0);          \
    ga1 = __builtin_amdgcn_mfma_f32_16x16x32_f16(Af[1][1], Xl1, ga1, 0,0,0);          \
    ga2 = __builtin_amdgcn_mfma_f32_16x16x32_f16(Af[2][1], Xl1, ga2, 0,0,0);          \
    ha0 = __builtin_amdgcn_mfma_f32_16x16x32_f16(Ah[0][1], Hl1, ha0, 0,0,0);          \
    ha1 = __builtin_amdgcn_mfma_f32_16x16x32_f16(Ah[1][1], Hl1, ha1, 0,0,0);          \
    ha2 = __builtin_amdgcn_mfma_f32_16x16x32_f16(Ah[2][1], Hl1, ha2, 0,0,0);          \
    ga0 = __builtin_amdgcn_mfma_f32_16x16x32_f16(Af[0][2], Xh2, ga0, 0,0,0);          \
    ga1 = __builtin_amdgcn_mfma_f32_16x16x32_f16(Af[1][2], Xh2, ga1, 0,0,0);          \
    ga2 = __builtin_amdgcn_mfma_f32_16x16x32_f16(Af[2][2], Xh2, ga2, 0,0,0);          \
    ga0 = __builtin_amdgcn_mfma_f32_16x16x32_f16(Af[0][2], Xl2, ga0, 0,0,0);          \
    ga1 = __builtin_amdgcn_mfma_f32_16x16x32_f16(Af[1][2], Xl2, ga1, 0,0,0);          \
    ga2 = __builtin_amdgcn_mfma_f32_16x16x32_f16(Af[2][2], Xl2, ga2, 0,0,0);          \
    _Pragma("unroll")                                                                 \
    for (int r = 0; r < 4; ++r){                                                      \
        float rr = sigm(ga0[r] + ha0[r]);                                             \
        float zz = sigm(ga1[r] + ha1[r]);                                             \
        float nn = tanh_f(ga2[r] + rr*ha2[r]);                                        \
        float hn2 = (1.0f - zz)*nn + zz*h[r];                                         \
        h[r] = (t < dl_g) ? hn2 : h[r];                                               \
    }                                                                                 \
    { float e0 = h[0]-(float)(_Float16)h[0], e1 = h[1]-(float)(_Float16)h[1];         \
      float e2 = h[2]-(float)(_Float16)h[2], e3 = h[3]-(float)(_Float16)h[3];         \
      *(uint2*)&hh2[((HB^1)*16+sc)*72 + w*16 + g4*4] =                                \
          uint2{packh2(h[0],h[1]), packh2(h[2],h[3])};                                \
      *(uint2*)&hl2[((HB^1)*16+sc)*72 + w*16 + g4*4] =                                \
          uint2{packh2(e0,e1), packh2(e2,e3)};                                        \
    }                                                                                 \
    __syncthreads();                                                                  \
}

    for (int tb = 0; tb < DM; tb += 6){
        GSTEP(0, r0a, r0b, r1a, r1b)
        GSTEP(1, r1a, r1b, r0a, r0b)
        GSTEP(2, r0a, r0b, r1a, r1b)
        GSTEP(3, r1a, r1b, r0a, r0b)
        GSTEP(4, r0a, r0b, r1a, r1b)
        GSTEP(5, r1a, r1b, r0a, r0b)
    }
#undef GSTEP

    // ---- forward output
    float mk = (dl_g > 0) ? 1.0f : 0.0f;
    {
        float4 o4 = {h[0]*mk, h[1]*mk, h[2]*mk, h[3]*mk};
        *(float4*)(out + ((size_t)sg*16 + sc)*(2*NH) + w*16 + g4*4) = o4;
    }

    // ---- backward GRU single step from h=0 on x_last (xlast complete: last
    // write was iter <= 46, final loop barrier covers it)
    half8 Afb[3][3];
    #pragma unroll
    for (int gt = 0; gt < 3; ++gt)
        #pragma unroll
        for (int ks = 0; ks < 3; ++ks)
            Afb[gt][ks] = *(const half8*)(wihb16 + (size_t)(((gt*4+w)*3 + ks)*64 + l)*8);
    f32x4 ab0, ab1, ab2;
    {
        float4 t0 = *(const float4*)(bihb + 0*64 + w*16 + g4*4);
        float4 t1 = *(const float4*)(bihb + 1*64 + w*16 + g4*4);
        float4 t2 = *(const float4*)(bihb + 2*64 + w*16 + g4*4);
        ab0[0]=t0.x; ab0[1]=t0.y; ab0[2]=t0.z; ab0[3]=t0.w;
        ab1[0]=t1.x; ab1[1]=t1.y; ab1[2]=t1.z; ab1[3]=t1.w;
        ab2[0]=t2.x; ab2[1]=t2.y; ab2[2]=t2.z; ab2[3]=t2.w;
    }
    #pragma unroll
    for (int ks = 0; ks < 3; ++ks){
        float4 xa = *(const float4*)&xlast[sc*100 + ks*32 + g4*8];
        float4 xb = *(const float4*)&xlast[sc*100 + ks*32 + g4*8 + 4];
        float xv[8] = {xa.x,xa.y,xa.z,xa.w, xb.x,xb.y,xb.z,xb.w};
        half8 Bh, Bl;
        #pragma unroll
        for (int i = 0; i < 8; ++i){
            _Float16 hi = (_Float16)xv[i];
            Bh[i] = hi;
            Bl[i] = (_Float16)(xv[i] - (float)hi);
        }
        ab0 = __builtin_amdgcn_mfma_f32_16x16x32_f16(Afb[0][ks], Bh, ab0, 0,0,0);
        ab1 = __builtin_amdgcn_mfma_f32_16x16x32_f16(Afb[1][ks], Bh, ab1, 0,0,0);
        ab2 = __builtin_amdgcn_mfma_f32_16x16x32_f16(Afb[2][ks], Bh, ab2, 0,0,0);
        ab0 = __builtin_amdgcn_mfma_f32_16x16x32_f16(Afb[0][ks], Bl, ab0, 0,0,0);
        ab1 = __builtin_amdgcn_mfma_f32_16x16x32_f16(Afb[1][ks], Bl, ab1, 0,0,0);
        ab2 = __builtin_amdgcn_mfma_f32_16x16x32_f16(Afb[2][ks], Bl, ab2, 0,0,0);
    }
    {
        float4 p0 = *(const float4*)(bhhb + 0*64 + w*16 + g4*4);
        float4 p1 = *(const float4*)(bhhb + 1*64 + w*16 + g4*4);
        float4 p2 = *(const float4*)(bhhb + 2*64 + w*16 + g4*4);
        float pr0[4] = {p0.x,p0.y,p0.z,p0.w};
        float pr1[4] = {p1.x,p1.y,p1.z,p1.w};
        float pr2[4] = {p2.x,p2.y,p2.z,p2.w};
        float ho[4];
        #pragma unroll
        for (int r = 0; r < 4; ++r){
            float rr = sigm(ab0[r] + pr0[r]);
            float zz = sigm(ab1[r] + pr1[r]);
            float nn = tanh_f(ab2[r] + rr*pr2[r]);
            ho[r] = (1.0f - zz)*nn * mk;
        }
        float4 o4 = {ho[0], ho[1], ho[2], ho[3]};
        *(float4*)(out + ((size_t)sg*16 + sc)*(2*NH) + NH + w*16 + g4*4) = o4;
    }
}

extern "C" void kernel_launch(void* const* d_in, const int* in_sizes, int n_in,
                              void* d_out, int out_size, void* d_ws, size_t ws_size,
                              hipStream_t stream){
    const float* mels = (const float*)d_in[0];
    const int*   dur  = (const int*)d_in[1];
    const float* cw = (const float*)d_in[3];
    const float* cb = (const float*)d_in[4];
    const float* bg = (const float*)d_in[5];
    const float* bb = (const float*)d_in[6];
    const float* bm = (const float*)d_in[7];
    const float* bv = (const float*)d_in[8];
    const float* Wihf = (const float*)d_in[9];
    const float* Whhf = (const float*)d_in[10];
    const float* bihf = (const float*)d_in[11];
    const float* bhhf = (const float*)d_in[12];
    const float* Wihb = (const float*)d_in[13];
    // d_in[14] = W_hh_b — unused (h0 = 0 => gh = bhh_b)
    const float* bihb = (const float*)d_in[15];
    const float* bhhb = (const float*)d_in[16];
    float* out = (float*)d_out;

    int*            starts = (int*)((char*)d_ws + WS_STARTS);
    unsigned short* wih16  = (unsigned short*)((char*)d_ws + WS_WIH);
    unsigned short* whh16  = (unsigned short*)((char*)d_ws + WS_WHH);
    unsigned short* wihb16 = (unsigned short*)((char*)d_ws + WS_WIHB);

    k_starts<<<NB, NP, 0, stream>>>(dur, starts);
    k_prep<<<192, 256, 0, stream>>>(Wihf, Whhf, Wihb, wih16, whh16, wihb16);
    k_fused<<<NSG, 256, 0, stream>>>(mels, starts, dur, wih16, whh16, wihb16,
                                     bihf, bhhf, bihb, bhhb,
                                     cw, cb, bg, bb, bm, bv, out);
}

// Round 5
// 220.043 us; speedup vs baseline: 2.7884x; 1.1132x over previous
//
#include <hip/hip_runtime.h>

#define NB 32
#define NP 192
#define DM 48          // max_dur
#define ND 80          // DMEL
#define NH 64          // H
#define NT (NP*DM)     // 9216
#define NBP (NB*NP)    // 6144
#define NSG (NBP/16)   // 384 blocks of 16 sequences

typedef _Float16 half8 __attribute__((ext_vector_type(8)));
typedef float f32x4 __attribute__((ext_vector_type(4)));

// workspace layout (bytes)
#define WS_STARTS 0                        // 6144 ints
#define WS_WIH   32768                     // 36864 B
#define WS_WHH   (32768 + 36864)           // 24576 B
#define WS_WIHB  (32768 + 36864 + 24576)   // 36864 B

__device__ __forceinline__ float sigm(float x){ return 1.0f/(1.0f + __expf(-x)); }
__device__ __forceinline__ float tanh_f(float x){ return 1.0f - 2.0f/(1.0f + __expf(2.0f*x)); }

__device__ __forceinline__ unsigned packh2(float a, float b){
    unsigned short ua = __builtin_bit_cast(unsigned short, (_Float16)a);
    unsigned short ub = __builtin_bit_cast(unsigned short, (_Float16)b);
    return (unsigned)ua | ((unsigned)ub << 16);
}

struct Aff { float a0,c0,a1,c1; };
__device__ __forceinline__ Aff make_aff(const float* cw, const float* cb, const float* bg,
                                        const float* bb, const float* bm, const float* bv){
    float s0 = bg[0]*rsqrtf(bv[0]+1e-5f);
    float s1 = bg[1]*rsqrtf(bv[1]+1e-5f);
    Aff A;
    A.a0 = cw[0]*s0; A.c0 = (cb[0]-bm[0])*s0 + bb[0];
    A.a1 = cw[1]*s1; A.c1 = (cb[1]-bm[1])*s1 + bb[1];
    return A;
}
__device__ __forceinline__ float aff(float x, const Aff A){
    float y = fmaxf(fmaf(A.a0, x, A.c0), 0.0f);
    return fmaxf(fmaf(A.a1, y, A.c1), 0.0f);
}

// lgkm-only fence + raw barrier: does NOT drain vmcnt (prefetch stays in flight)
__device__ __forceinline__ void lds_barrier(){
    asm volatile("s_waitcnt lgkmcnt(0)" ::: "memory");
    __builtin_amdgcn_s_barrier();
    asm volatile("" ::: "memory");
}

// ---------------- K1: exclusive cumsum of durations -> starts ----------------
__global__ __launch_bounds__(NP) void k_starts(const int* __restrict__ dur,
                                               int* __restrict__ starts){
    __shared__ int s[NP];
    int b = blockIdx.x, p = threadIdx.x;
    int d = dur[b*NP + p];
    s[p] = d;
    __syncthreads();
    #pragma unroll
    for (int off = 1; off < NP; off <<= 1){
        int v = (p >= off) ? s[p - off] : 0;
        __syncthreads();
        s[p] += v;
        __syncthreads();
    }
    starts[b*NP + p] = s[p] - d;   // exclusive
}

// ---------------- K_prep: f16 MFMA A-fragment layout for Wih_f, Whh_f, Wih_b
// A value at lane l, slot (ks,i): W[j][k], j = (f>>2)*64 + (f&3)*16 + (l&15),
// k = ks*32 + (l>>4)*8 + i   (f = gate*4 + wave)
__global__ __launch_bounds__(256) void k_prep(const float* __restrict__ Wih,
                                              const float* __restrict__ Whh,
                                              const float* __restrict__ Wihb,
                                              unsigned short* __restrict__ wih16,
                                              unsigned short* __restrict__ whh16,
                                              unsigned short* __restrict__ wihb16){
    int idx = blockIdx.x*256 + threadIdx.x;
    if (idx < 12*3*64*8){
        int i = idx & 7, l = (idx>>3) & 63, ks = (idx>>9) % 3, f = idx / 1536;
        int j = (f>>2)*64 + (f&3)*16 + (l&15);
        int k = ks*32 + (l>>4)*8 + i;
        float v = (k < ND) ? Wih[j*ND + k] : 0.0f;
        wih16[idx] = __builtin_bit_cast(unsigned short, (_Float16)v);
        return;
    }
    int idx2 = idx - 12*3*64*8;
    if (idx2 < 12*2*64*8){
        int i = idx2 & 7, l = (idx2>>3) & 63, ks = (idx2>>9) & 1, f = idx2 / 1024;
        int j = (f>>2)*64 + (f&3)*16 + (l&15);
        int k = ks*32 + (l>>4)*8 + i;
        whh16[idx2] = __builtin_bit_cast(unsigned short, (_Float16)Whh[j*NH + k]);
        return;
    }
    int idx3 = idx2 - 12*2*64*8;
    if (idx3 < 12*3*64*8){
        int i = idx3 & 7, l = (idx3>>3) & 63, ks = (idx3>>9) % 3, f = idx3 / 1536;
        int j = (f>>2)*64 + (f&3)*16 + (l&15);
        int k = ks*32 + (l>>4)*8 + i;
        float v = (k < ND) ? Wihb[j*ND + k] : 0.0f;
        wihb16[idx3] = __builtin_bit_cast(unsigned short, (_Float16)v);
    }
}

// ---------------- K_fused: gather+affine + gi MFMA + GRU + bwd epilogue -----
// Block: 16 seqs, 4 waves. x LDS layout frag-linear: xf[buf][ks*64+l] uint4
// holds x[sc=l&15][k = ks*32 + (l>>4)*8 .. +7] as 8 f16 (single precision-level).
// h kept hi/lo f16 (error-compounding path). Raw lgkm barrier: global prefetch
// (issued 2 steps ahead) is never drained by the per-step barrier.
__global__ __launch_bounds__(256, 2) void k_fused(
        const float* __restrict__ mels,
        const int* __restrict__ starts,
        const int* __restrict__ dur,
        const unsigned short* __restrict__ wih16,
        const unsigned short* __restrict__ whh16,
        const unsigned short* __restrict__ wihb16,
        const float* __restrict__ bih,  const float* __restrict__ bhh,
        const float* __restrict__ bihb, const float* __restrict__ bhhb,
        const float* __restrict__ cw, const float* __restrict__ cb,
        const float* __restrict__ bg, const float* __restrict__ bb,
        const float* __restrict__ bm, const float* __restrict__ bv,
        float* __restrict__ out){
    __shared__ alignas(16) uint4 xf[3*192];            // 9216 B, conflict-free
    __shared__ alignas(16) uint4 xlast[192];           // 3072 B
    __shared__ alignas(16) unsigned short hh2[2*1152]; // 2 buf x 16 seq x 72
    __shared__ alignas(16) unsigned short hl2[2*1152];

    int sg  = blockIdx.x;
    int tid = threadIdx.x;
    int w = tid >> 6, l = tid & 63;
    int sc = l & 15, g4 = l >> 4;
    Aff A = make_aff(cw,cb,bg,bb,bm,bv);

    // A fragments
    half8 Af[3][3], Ah[3][2];
    #pragma unroll
    for (int gt = 0; gt < 3; ++gt){
        #pragma unroll
        for (int ks = 0; ks < 3; ++ks)
            Af[gt][ks] = *(const half8*)(wih16 + (size_t)(((gt*4+w)*3 + ks)*64 + l)*8);
        #pragma unroll
        for (int ks = 0; ks < 2; ++ks)
            Ah[gt][ks] = *(const half8*)(whh16 + (size_t)(((gt*4+w)*2 + ks)*64 + l)*8);
    }
    f32x4 bi[3], bh[3];
    #pragma unroll
    for (int gt = 0; gt < 3; ++gt){
        float4 t4 = *(const float4*)(bih + gt*64 + w*16 + g4*4);
        bi[gt][0]=t4.x; bi[gt][1]=t4.y; bi[gt][2]=t4.z; bi[gt][3]=t4.w;
        float4 u4 = *(const float4*)(bhh + gt*64 + w*16 + g4*4);
        bh[gt][0]=u4.x; bh[gt][1]=u4.y; bh[gt][2]=u4.z; bh[gt][3]=u4.w;
    }
    int dl_g = dur[sg*16 + sc];

    // staging role: thread tid<192 owns unit (ks_s = tid/64, l_s = tid&63)
    //   -> 8 consecutive k = k0..k0+7 of seq sc_s
    bool stg = (tid < 192);
    int ks_s = tid >> 6, ls = tid & 63;
    int scs = ls & 15, g4s = ls >> 4;
    int k0 = ks_s*32 + g4s*8;
    bool valid = stg && (k0 < ND);
    int st_s = 0, d_s = -1;
    if (stg){ st_s = starts[sg*16 + scs]; d_s = dur[sg*16 + scs]; }
    const float* mb = mels + (size_t)(sg/12)*NT*ND;

    auto ld2 = [&](int t, float4& va, float4& vb){
        int r = st_s + t; r = (r < NT-1) ? r : (NT-1);
        const float* p = mb + (size_t)r*ND + k0;
        va = *(const float4*)p;
        vb = *(const float4*)(p + 4);
    };
    auto stage = [&](int pw, int tt, float4 va, float4 vb){
        if (valid){
            float y0=aff(va.x,A), y1=aff(va.y,A), y2=aff(va.z,A), y3=aff(va.w,A);
            float y4=aff(vb.x,A), y5=aff(vb.y,A), y6=aff(vb.z,A), y7=aff(vb.w,A);
            uint4 P = uint4{packh2(y0,y1), packh2(y2,y3), packh2(y4,y5), packh2(y6,y7)};
            xf[pw*192 + tid] = P;
            if (tt == d_s - 1) xlast[tid] = P;
        }
    };

    // ---- prologue: zero pads (k>=80 region, all 3 bufs + xlast), zero h bufs
    if (stg && !valid){
        uint4 z = uint4{0,0,0,0};
        xf[0*192 + tid] = z; xf[1*192 + tid] = z; xf[2*192 + tid] = z;
        xlast[tid] = z;
    }
    for (int i = tid; i < 288; i += 256){   // 2*1152 shorts = 288 uint4
        ((uint4*)hh2)[i] = uint4{0,0,0,0};
        ((uint4*)hl2)[i] = uint4{0,0,0,0};
    }
    float4 va0 = {0,0,0,0}, vb0 = {0,0,0,0}, va1 = {0,0,0,0}, vb1 = {0,0,0,0};
    if (valid) ld2(0, va0, vb0);
    stage(0, 0, va0, vb0);
    if (valid) ld2(1, va0, vb0);     // set0 now holds x(1)
    float h[4] = {0.f,0.f,0.f,0.f};
    lds_barrier();

#define MFMA(a,b,c) __builtin_amdgcn_mfma_f32_16x16x32_f16(a,b,c,0,0,0)
#define GSTEP(K, SA, SB, LA, LB)                                                      \
{                                                                                     \
    const int PR = (K) % 3, PW = ((K)+1) % 3, HB = (K) & 1;                           \
    const int t = tb + (K);                                                           \
    half8 X0  = *(const half8*)&xf[PR*192 +   0 + l];                                 \
    half8 X1  = *(const half8*)&xf[PR*192 +  64 + l];                                 \
    half8 X2  = *(const half8*)&xf[PR*192 + 128 + l];                                 \
    half8 Hh0 = *(const half8*)&hh2[HB*1152 + sc*72 +  0 + g4*8];                     \
    half8 Hh1 = *(const half8*)&hh2[HB*1152 + sc*72 + 32 + g4*8];                     \
    half8 Hl0 = *(const half8*)&hl2[HB*1152 + sc*72 +  0 + g4*8];                     \
    half8 Hl1 = *(const half8*)&hl2[HB*1152 + sc*72 + 32 + g4*8];                     \
    if (t+1 < DM) stage(PW, t+1, SA, SB);                                             \
    if (valid && (t+2 < DM)) ld2(t+2, LA, LB);                                        \
    f32x4 ga0 = bi[0], ga1 = bi[1], ga2 = bi[2];                                      \
    f32x4 ha0 = bh[0], ha1 = bh[1], ha2 = bh[2];                                      \
    ha0 = MFMA(Ah[0][0], Hh0, ha0); ha1 = MFMA(Ah[1][0], Hh0, ha1);                   \
    ha2 = MFMA(Ah[2][0], Hh0, ha2);                                                   \
    ga0 = MFMA(Af[0][0], X0, ga0);  ga1 = MFMA(Af[1][0], X0, ga1);                    \
    ga2 = MFMA(Af[2][0], X0, ga2);                                                    \
    ha0 = MFMA(Ah[0][0], Hl0, ha0); ha1 = MFMA(Ah[1][0], Hl0, ha1);                   \
    ha2 = MFMA(Ah[2][0], Hl0, ha2);                                                   \
    ga0 = MFMA(Af[0][1], X1, ga0);  ga1 = MFMA(Af[1][1], X1, ga1);                    \
    ga2 = MFMA(Af[2][1], X1, ga2);                                                    \
    ha0 = MFMA(Ah[0][1], Hh1, ha0); ha1 = MFMA(Ah[1][1], Hh1, ha1);                   \
    ha2 = MFMA(Ah[2][1], Hh1, ha2);                                                   \
    ha0 = MFMA(Ah[0][1], Hl1, ha0); ha1 = MFMA(Ah[1][1], Hl1, ha1);                   \
    ha2 = MFMA(Ah[2][1], Hl1, ha2);                                                   \
    ga0 = MFMA(Af[0][2], X2, ga0);  ga1 = MFMA(Af[1][2], X2, ga1);                    \
    ga2 = MFMA(Af[2][2], X2, ga2);                                                    \
    _Pragma("unroll")                                                                 \
    for (int r = 0; r < 4; ++r){                                                      \
        float rr = sigm(ga0[r] + ha0[r]);                                             \
        float zz = sigm(ga1[r] + ha1[r]);                                             \
        float nn = tanh_f(ga2[r] + rr*ha2[r]);                                        \
        float hn2 = (1.0f - zz)*nn + zz*h[r];                                         \
        h[r] = (t < dl_g) ? hn2 : h[r];                                               \
    }                                                                                 \
    { float e0 = h[0]-(float)(_Float16)h[0], e1 = h[1]-(float)(_Float16)h[1];         \
      float e2 = h[2]-(float)(_Float16)h[2], e3 = h[3]-(float)(_Float16)h[3];         \
      *(uint2*)&hh2[(HB^1)*1152 + sc*72 + w*16 + g4*4] =                              \
          uint2{packh2(h[0],h[1]), packh2(h[2],h[3])};                                \
      *(uint2*)&hl2[(HB^1)*1152 + sc*72 + w*16 + g4*4] =                              \
          uint2{packh2(e0,e1), packh2(e2,e3)};                                        \
    }                                                                                 \
    lds_barrier();                                                                    \
}

    for (int tb = 0; tb < DM; tb += 6){
        GSTEP(0, va0, vb0, va1, vb1)
        GSTEP(1, va1, vb1, va0, vb0)
        GSTEP(2, va0, vb0, va1, vb1)
        GSTEP(3, va1, vb1, va0, vb0)
        GSTEP(4, va0, vb0, va1, vb1)
        GSTEP(5, va1, vb1, va0, vb0)
    }
#undef GSTEP

    // ---- forward output
    float mk = (dl_g > 0) ? 1.0f : 0.0f;
    {
        float4 o4 = {h[0]*mk, h[1]*mk, h[2]*mk, h[3]*mk};
        *(float4*)(out + ((size_t)sg*16 + sc)*(2*NH) + w*16 + g4*4) = o4;
    }

    // ---- backward GRU single step from h=0 on xlast (frag-ready f16)
    half8 Afb[3][3];
    #pragma unroll
    for (int gt = 0; gt < 3; ++gt)
        #pragma unroll
        for (int ks = 0; ks < 3; ++ks)
            Afb[gt][ks] = *(const half8*)(wihb16 + (size_t)(((gt*4+w)*3 + ks)*64 + l)*8);
    f32x4 ab0, ab1, ab2;
    {
        float4 t0 = *(const float4*)(bihb + 0*64 + w*16 + g4*4);
        float4 t1 = *(const float4*)(bihb + 1*64 + w*16 + g4*4);
        float4 t2 = *(const float4*)(bihb + 2*64 + w*16 + g4*4);
        ab0[0]=t0.x; ab0[1]=t0.y; ab0[2]=t0.z; ab0[3]=t0.w;
        ab1[0]=t1.x; ab1[1]=t1.y; ab1[2]=t1.z; ab1[3]=t1.w;
        ab2[0]=t2.x; ab2[1]=t2.y; ab2[2]=t2.z; ab2[3]=t2.w;
    }
    #pragma unroll
    for (int ks = 0; ks < 3; ++ks){
        half8 Bx = *(const half8*)&xlast[ks*64 + l];
        ab0 = MFMA(Afb[0][ks], Bx, ab0);
        ab1 = MFMA(Afb[1][ks], Bx, ab1);
        ab2 = MFMA(Afb[2][ks], Bx, ab2);
    }
    {
        float4 p0 = *(const float4*)(bhhb + 0*64 + w*16 + g4*4);
        float4 p1 = *(const float4*)(bhhb + 1*64 + w*16 + g4*4);
        float4 p2 = *(const float4*)(bhhb + 2*64 + w*16 + g4*4);
        float pr0[4] = {p0.x,p0.y,p0.z,p0.w};
        float pr1[4] = {p1.x,p1.y,p1.z,p1.w};
        float pr2[4] = {p2.x,p2.y,p2.z,p2.w};
        float ho[4];
        #pragma unroll
        for (int r = 0; r < 4; ++r){
            float rr = sigm(ab0[r] + pr0[r]);
            float zz = sigm(ab1[r] + pr1[r]);
            float nn = tanh_f(ab2[r] + rr*pr2[r]);
            ho[r] = (1.0f - zz)*nn * mk;
        }
        float4 o4 = {ho[0], ho[1], ho[2], ho[3]};
        *(float4*)(out + ((size_t)sg*16 + sc)*(2*NH) + NH + w*16 + g4*4) = o4;
    }
#undef MFMA
}

extern "C" void kernel_launch(void* const* d_in, const int* in_sizes, int n_in,
                              void* d_out, int out_size, void* d_ws, size_t ws_size,
                              hipStream_t stream){
    const float* mels = (const float*)d_in[0];
    const int*   dur  = (const int*)d_in[1];
    const float* cw = (const float*)d_in[3];
    const float* cb = (const float*)d_in[4];
    const float* bg = (const float*)d_in[5];
    const float* bb = (const float*)d_in[6];
    const float* bm = (const float*)d_in[7];
    const float* bv = (const float*)d_in[8];
    const float* Wihf = (const float*)d_in[9];
    const float* Whhf = (const float*)d_in[10];
    const float* bihf = (const float*)d_in[11];
    const float* bhhf = (const float*)d_in[12];
    const float* Wihb = (const float*)d_in[13];
    // d_in[14] = W_hh_b — unused (h0 = 0 => gh = bhh_b)
    const float* bihb = (const float*)d_in[15];
    const float* bhhb = (const float*)d_in[16];
    float* out = (float*)d_out;

    int*            starts = (int*)((char*)d_ws + WS_STARTS);
    unsigned short* wih16  = (unsigned short*)((char*)d_ws + WS_WIH);
    unsigned short* whh16  = (unsigned short*)((char*)d_ws + WS_WHH);
    unsigned short* wihb16 = (unsigned short*)((char*)d_ws + WS_WIHB);

    k_starts<<<NB, NP, 0, stream>>>(dur, starts);
    k_prep<<<192, 256, 0, stream>>>(Wihf, Whhf, Wihb, wih16, whh16, wihb16);
    k_fused<<<NSG, 256, 0, stream>>>(mels, starts, dur, wih16, whh16, wihb16,
                                     bihf, bhhf, bihb, bhhb,
                                     cw, cb, bg, bb, bm, bv, out);
}